// Round 1
// baseline (321.956 us; speedup 1.0000x reference)
//
#include <hip/hip_runtime.h>
#include <hip/hip_fp16.h>
#include <math.h>

typedef _Float16 f16;
typedef __attribute__((ext_vector_type(4))) _Float16 f16x4;
typedef __attribute__((ext_vector_type(8))) _Float16 f16x8;
typedef __attribute__((ext_vector_type(4))) float f32x4;

static constexpr int NBATCH = 4, DK = 128, DV = 512, L = 4096;
static constexpr float PSCALE = 256.f; // keep p' out of fp16-denormal range

__device__ __forceinline__ void async16(const void* g, void* l) {
  __builtin_amdgcn_global_load_lds((const __attribute__((address_space(1))) void*)g,
                                   (__attribute__((address_space(3))) void*)l, 16, 0, 0);
}

// [B][rows][cols] f32 -> [B][cols][rows] f16  (rows=128, cols=4096)
__global__ void k_tr_f32_f16(const float* __restrict__ in, f16* __restrict__ out,
                             int rows, int cols) {
  __shared__ float tile[32][33];
  const size_t bs = (size_t)rows * cols;
  const float* inb = in + (size_t)blockIdx.z * bs;
  f16* outb = out + (size_t)blockIdx.z * bs;
  const int c0 = blockIdx.x * 32, r0 = blockIdx.y * 32;
  const int tx = threadIdx.x, ty = threadIdx.y;
#pragma unroll
  for (int i = 0; i < 32; i += 8)
    tile[ty + i][tx] = inb[(size_t)(r0 + ty + i) * cols + (c0 + tx)];
  __syncthreads();
#pragma unroll
  for (int i = 0; i < 32; i += 8)
    outb[(size_t)(c0 + ty + i) * rows + (r0 + tx)] = (f16)tile[tx][ty + i];
}

__global__ void k_cvt_f16(const float4* __restrict__ in, f16x4* __restrict__ out, int n4) {
  int i = blockIdx.x * blockDim.x + threadIdx.x;
  const int st = gridDim.x * blockDim.x;
  for (; i < n4; i += st) {
    float4 v = in[i];
    f16x4 o;
    o.x = (f16)v.x; o.y = (f16)v.y; o.z = (f16)v.z; o.w = (f16)v.w;
    out[i] = o;
  }
}

// C[z][row][col] = oscale * sum_k A[z][row][k] * B[z][col][k]
// A:[M][K] f16 row-major, B:[N][K] f16 row-major (both K-contiguous).
// 128x128 tile, BK=64, 4 waves (2x2), global_load_lds with XOR-source-swizzle.
template<bool OUT_F16>
__global__ __launch_bounds__(256, 2)
void k_gemm_bt(const f16* __restrict__ A, const f16* __restrict__ B,
               void* __restrict__ C, int M, int N, int K, float oscale) {
  constexpr int BK = 64;
  __shared__ __align__(16) f16 As[128 * BK];
  __shared__ __align__(16) f16 Bs[128 * BK];
  const int z = blockIdx.z;
  const f16* Ab = A + (size_t)z * M * K;
  const f16* Bbp = B + (size_t)z * N * K;
  const int row0 = blockIdx.y * 128, col0 = blockIdx.x * 128;
  const int tid = threadIdx.x, lane = tid & 63, wv = tid >> 6;
  const int wr = wv >> 1, wc = wv & 1;
  f32x4 acc[4][4] = {};
  // staging: wave wv stages rows [32wv,32wv+32) of A and B; 8 rows per call.
  // LDS is linear [row][64k]; source chunk pre-swizzled: clog = cphys ^ (row&7)
  const int srow = wv * 32 + (lane >> 3);
  const int sc = (lane & 7) ^ (lane >> 3); // (cphys=lane&7) ^ (row&7 = lane>>3)
  const f16* aSrc = Ab + (size_t)(row0 + srow) * K + sc * 8;
  const f16* bSrc = Bbp + (size_t)(col0 + srow) * K + sc * 8;
  f16* aDst = &As[(wv * 32) * BK];
  f16* bDst = &Bs[(wv * 32) * BK];

  for (int k0 = 0; k0 < K; k0 += BK) {
    __syncthreads(); // previous tile fully consumed
#pragma unroll
    for (int j = 0; j < 4; ++j) {
      async16(aSrc + (size_t)(j * 8) * K + k0, aDst + (j * 8) * BK);
      async16(bSrc + (size_t)(j * 8) * K + k0, bDst + (j * 8) * BK);
    }
    __syncthreads(); // loads landed (compiler drains vmcnt before barrier)
#pragma unroll
    for (int kk = 0; kk < BK / 32; ++kk) {
      const int cx = ((kk * 4 + (lane >> 4)) ^ (lane & 7)) * 8; // swizzled chunk
      f16x8 av[4], bv[4];
#pragma unroll
      for (int i = 0; i < 4; ++i) {
        av[i] = *(const f16x8*)&As[(wr * 64 + i * 16 + (lane & 15)) * BK + cx];
        bv[i] = *(const f16x8*)&Bs[(wc * 64 + i * 16 + (lane & 15)) * BK + cx];
      }
#pragma unroll
      for (int i = 0; i < 4; ++i)
#pragma unroll
        for (int j = 0; j < 4; ++j)
          acc[i][j] = __builtin_amdgcn_mfma_f32_16x16x32_f16(av[i], bv[j], acc[i][j], 0, 0, 0);
    }
  }
  // C/D layout: col = lane&15, row = (lane>>4)*4 + t
  const size_t cb = (size_t)z * M * N;
  const int er = (lane >> 4) * 4, ec = lane & 15;
#pragma unroll
  for (int i = 0; i < 4; ++i) {
    const int r = row0 + wr * 64 + i * 16 + er;
#pragma unroll
    for (int j = 0; j < 4; ++j) {
      const int c = col0 + wc * 64 + j * 16 + ec;
#pragma unroll
      for (int t = 0; t < 4; ++t) {
        const float v = acc[i][j][t] * oscale;
        if (OUT_F16) ((f16*)C)[cb + (size_t)(r + t) * N + c] = (f16)v;
        else        ((float*)C)[cb + (size_t)(r + t) * N + c] = v;
      }
    }
  }
}

// in-place row softmax over L=4096 fp16 values; one block (256 thr) per row.
// writes p * PSCALE.
__global__ __launch_bounds__(256)
void k_softmax(f16* __restrict__ S) {
  const size_t rowbase = (size_t)blockIdx.x * L;
  const int tid = threadIdx.x, ln = tid & 63, wv = tid >> 6;
  f16* p = S + rowbase + tid * 16;
  f16x8 v0 = *(const f16x8*)p;
  f16x8 v1 = *(const f16x8*)(p + 8);
  float x[16];
#pragma unroll
  for (int j = 0; j < 8; ++j) { x[j] = (float)v0[j]; x[8 + j] = (float)v1[j]; }
  float m = -3.0e38f;
#pragma unroll
  for (int j = 0; j < 16; ++j) m = fmaxf(m, x[j]);
#pragma unroll
  for (int off = 1; off < 64; off <<= 1) m = fmaxf(m, __shfl_xor(m, off));
  __shared__ float redm[4], reds[4];
  if (ln == 0) redm[wv] = m;
  __syncthreads();
  m = fmaxf(fmaxf(redm[0], redm[1]), fmaxf(redm[2], redm[3]));
  float s = 0.f;
#pragma unroll
  for (int j = 0; j < 16; ++j) { x[j] = __expf(x[j] - m); s += x[j]; }
#pragma unroll
  for (int off = 1; off < 64; off <<= 1) s += __shfl_xor(s, off);
  if (ln == 0) reds[wv] = s;
  __syncthreads();
  s = (reds[0] + reds[1]) + (reds[2] + reds[3]);
  const float k = PSCALE / s;
#pragma unroll
  for (int j = 0; j < 8; ++j) { v0[j] = (f16)(x[j] * k); v1[j] = (f16)(x[8 + j] * k); }
  *(f16x8*)p = v0;
  *(f16x8*)(p + 8) = v1;
}

// p f32 [m][q] = scale * (f32) p' f16 [q][m]   (one batch, 64x64 tiles)
__global__ __launch_bounds__(256)
void k_tr_out(const f16* __restrict__ src, float* __restrict__ dst, float scale) {
  __shared__ float tile[64][65];
  const int m0 = blockIdx.x * 64, q0 = blockIdx.y * 64;
  const int tid = threadIdx.x;
  const int r = tid >> 2, c4 = (tid & 3) * 16;
  const f16* sp = src + (size_t)(q0 + r) * L + m0 + c4;
  f16x8 a = *(const f16x8*)sp;
  f16x8 b = *(const f16x8*)(sp + 8);
#pragma unroll
  for (int j = 0; j < 8; ++j) {
    tile[c4 + j][r] = (float)a[j] * scale;
    tile[c4 + 8 + j][r] = (float)b[j] * scale;
  }
  __syncthreads();
  float* dp = dst + (size_t)(m0 + r) * L + q0 + c4;
#pragma unroll
  for (int g = 0; g < 4; ++g) {
    float4 w;
    w.x = tile[r][c4 + 4 * g + 0];
    w.y = tile[r][c4 + 4 * g + 1];
    w.z = tile[r][c4 + 4 * g + 2];
    w.w = tile[r][c4 + 4 * g + 3];
    *(float4*)(dp + 4 * g) = w;
  }
}

extern "C" void kernel_launch(void* const* d_in, const int* in_sizes, int n_in,
                              void* d_out, int out_size, void* d_ws, size_t ws_size,
                              hipStream_t stream) {
  const float* m_k = (const float*)d_in[0];
  const float* m_v = (const float*)d_in[1];
  const float* q_k = (const float*)d_in[2];
  char* ws = (char*)d_ws;
  f16* bounce = (f16*)ws;                             // 32 MiB
  f16* qkT = (f16*)(ws + ((size_t)32 << 20));         // 4 MiB  [B][Lq][Dk]
  f16* mkT = (f16*)(ws + ((size_t)36 << 20));         // 4 MiB  [B][Lm][Dk]
  f16* mvh = (f16*)(ws + ((size_t)40 << 20));         // 16 MiB [B][Dv][Lm]
  float* memOut = (float*)d_out;                      // [B][Dv][L]
  float* pOut = memOut + (size_t)NBATCH * DV * L;     // [B][L][L] f32
  f16* pp = (f16*)(pOut + (size_t)NBATCH * L * L / 2);// upper half: p' f16 [B][Lq][Lm]

  dim3 tb(32, 8, 1);
  k_tr_f32_f16<<<dim3(L / 32, DK / 32, NBATCH), tb, 0, stream>>>(q_k, qkT, DK, L);
  k_tr_f32_f16<<<dim3(L / 32, DK / 32, NBATCH), tb, 0, stream>>>(m_k, mkT, DK, L);
  k_cvt_f16<<<2048, 256, 0, stream>>>((const float4*)m_v, (f16x4*)mvh,
                                      NBATCH * DV * L / 4);
  // S'[q][m] = qkT . mkT^T / sqrt(Dk)  (fp16 out, into pp)
  k_gemm_bt<true><<<dim3(L / 128, L / 128, NBATCH), 256, 0, stream>>>(
      qkT, mkT, (void*)pp, L, L, DK, 0.08838834764831845f);
  // row softmax in place (over m) -> p' * 256
  k_softmax<<<NBATCH * L, 256, 0, stream>>>(pp);
  // save batch-3 p' before the f32 transpose overwrites its storage
  hipMemcpyAsync(bounce, pp + (size_t)3 * L * L, (size_t)L * L * sizeof(f16),
                 hipMemcpyDeviceToDevice, stream);
  // mem[v][q] = sum_m mv[v][m] * p'[q][m] / 256
  k_gemm_bt<false><<<dim3(L / 128, DV / 128, NBATCH), 256, 0, stream>>>(
      mvh, pp, (void*)memOut, DV, L, L, 1.f / PSCALE);
  // p f32 [m][q] per batch; batches in order so writes never clobber unread p'
  for (int b = 0; b < NBATCH; ++b) {
    const f16* src = (b == 3) ? bounce : (pp + (size_t)b * L * L);
    k_tr_out<<<dim3(L / 64, L / 64), 256, 0, stream>>>(
        src, pOut + (size_t)b * L * L, 1.f / PSCALE);
  }
  (void)in_sizes; (void)n_in; (void)out_size; (void)ws_size;
}

// Round 2
// 318.159 us; speedup vs baseline: 1.0119x; 1.0119x over previous
//
#include <hip/hip_runtime.h>
#include <hip/hip_fp16.h>
#include <math.h>

typedef _Float16 f16;
typedef __attribute__((ext_vector_type(4))) _Float16 f16x4;
typedef __attribute__((ext_vector_type(8))) _Float16 f16x8;
typedef __attribute__((ext_vector_type(4))) float f32x4;

static constexpr int NBATCH = 4, DK = 128, DV = 512, L = 4096;
static constexpr float PSCALE = 256.f; // keep p' out of fp16-denormal range

__device__ __forceinline__ void async16(const void* g, void* l) {
  __builtin_amdgcn_global_load_lds((const __attribute__((address_space(1))) void*)g,
                                   (__attribute__((address_space(3))) void*)l, 16, 0, 0);
}

// [B][rows][cols] f32 -> [B][cols][rows] f16  (rows=128, cols=4096)
__global__ void k_tr_f32_f16(const float* __restrict__ in, f16* __restrict__ out,
                             int rows, int cols) {
  __shared__ float tile[32][33];
  const size_t bs = (size_t)rows * cols;
  const float* inb = in + (size_t)blockIdx.z * bs;
  f16* outb = out + (size_t)blockIdx.z * bs;
  const int c0 = blockIdx.x * 32, r0 = blockIdx.y * 32;
  const int tx = threadIdx.x, ty = threadIdx.y;
#pragma unroll
  for (int i = 0; i < 32; i += 8)
    tile[ty + i][tx] = inb[(size_t)(r0 + ty + i) * cols + (c0 + tx)];
  __syncthreads();
#pragma unroll
  for (int i = 0; i < 32; i += 8)
    outb[(size_t)(c0 + ty + i) * rows + (r0 + tx)] = (f16)tile[tx][ty + i];
}

__global__ void k_cvt_f16(const float4* __restrict__ in, f16x4* __restrict__ out, int n4) {
  int i = blockIdx.x * blockDim.x + threadIdx.x;
  const int st = gridDim.x * blockDim.x;
  for (; i < n4; i += st) {
    float4 v = in[i];
    f16x4 o;
    o.x = (f16)v.x; o.y = (f16)v.y; o.z = (f16)v.z; o.w = (f16)v.w;
    out[i] = o;
  }
}

// C[z][row][col] = oscale * sum_k A[z][row][k] * B[z][col][k]
// A:[M][K] f16 row-major, B:[N][K] f16 row-major (both K-contiguous).
// 128x128 tile, BK=64, 4 waves (2x2), global_load_lds with XOR-source-swizzle.
// XCD-aware bijective swizzle on (x,y) when grid count %8==0 (T1).
template<bool OUT_F16>
__global__ __launch_bounds__(256, 2)
void k_gemm_bt(const f16* __restrict__ A, const f16* __restrict__ B,
               void* __restrict__ C, int M, int N, int K, float oscale) {
  constexpr int BK = 64;
  __shared__ __align__(16) f16 As[128 * BK];
  __shared__ __align__(16) f16 Bs[128 * BK];
  const int z = blockIdx.z;
  int bx = blockIdx.x, by = blockIdx.y;
  {
    const int n = gridDim.x * gridDim.y;
    if (!(n & 7)) {
      const int id = bx + gridDim.x * by;
      const int id2 = (id & 7) * (n >> 3) + (id >> 3);
      bx = id2 % gridDim.x;
      by = id2 / gridDim.x;
    }
  }
  const f16* Ab = A + (size_t)z * M * K;
  const f16* Bbp = B + (size_t)z * N * K;
  const int row0 = by * 128, col0 = bx * 128;
  const int tid = threadIdx.x, lane = tid & 63, wv = tid >> 6;
  const int wr = wv >> 1, wc = wv & 1;
  f32x4 acc[4][4] = {};
  // staging: wave wv stages rows [32wv,32wv+32) of A and B; 8 rows per call.
  // LDS is linear [row][64k]; source chunk pre-swizzled: clog = cphys ^ (row&7)
  const int srow = wv * 32 + (lane >> 3);
  const int sc = (lane & 7) ^ (lane >> 3); // (cphys=lane&7) ^ (row&7 = lane>>3)
  const f16* aSrc = Ab + (size_t)(row0 + srow) * K + sc * 8;
  const f16* bSrc = Bbp + (size_t)(col0 + srow) * K + sc * 8;
  f16* aDst = &As[(wv * 32) * BK];
  f16* bDst = &Bs[(wv * 32) * BK];

  for (int k0 = 0; k0 < K; k0 += BK) {
    __syncthreads(); // previous tile fully consumed
#pragma unroll
    for (int j = 0; j < 4; ++j) {
      async16(aSrc + (size_t)(j * 8) * K + k0, aDst + (j * 8) * BK);
      async16(bSrc + (size_t)(j * 8) * K + k0, bDst + (j * 8) * BK);
    }
    __syncthreads(); // loads landed (compiler drains vmcnt before barrier)
#pragma unroll
    for (int kk = 0; kk < BK / 32; ++kk) {
      const int cx = ((kk * 4 + (lane >> 4)) ^ (lane & 7)) * 8; // swizzled chunk
      f16x8 av[4], bv[4];
#pragma unroll
      for (int i = 0; i < 4; ++i) {
        av[i] = *(const f16x8*)&As[(wr * 64 + i * 16 + (lane & 15)) * BK + cx];
        bv[i] = *(const f16x8*)&Bs[(wc * 64 + i * 16 + (lane & 15)) * BK + cx];
      }
#pragma unroll
      for (int i = 0; i < 4; ++i)
#pragma unroll
        for (int j = 0; j < 4; ++j)
          acc[i][j] = __builtin_amdgcn_mfma_f32_16x16x32_f16(av[i], bv[j], acc[i][j], 0, 0, 0);
    }
  }
  // C/D layout: col = lane&15, row = (lane>>4)*4 + t
  const size_t cb = (size_t)z * M * N;
  const int er = (lane >> 4) * 4, ec = lane & 15;
#pragma unroll
  for (int i = 0; i < 4; ++i) {
    const int r = row0 + wr * 64 + i * 16 + er;
#pragma unroll
    for (int j = 0; j < 4; ++j) {
      const int c = col0 + wc * 64 + j * 16 + ec;
#pragma unroll
      for (int t = 0; t < 4; ++t) {
        const float v = acc[i][j][t] * oscale;
        if (OUT_F16) ((f16*)C)[cb + (size_t)(r + t) * N + c] = (f16)v;
        else        ((float*)C)[cb + (size_t)(r + t) * N + c] = v;
      }
    }
  }
}

// ---------------- fused softmax + transpose (fused path) ----------------
// S: [B][Lq][Lm] f16 raw scores (in ws). In place: p' = softmax_m * PSCALE.
// D: [B][Lm][Lq] f32 normalized p (d_out region).
// Block: 512 thr, 64 q-rows. 8 threads per row (seg = tid&7).
__global__ __launch_bounds__(512)
void k_smtr(f16* __restrict__ S0, float* __restrict__ D0) {
  __shared__ float tile[64][65];
  const int b = blockIdx.y;
  const int q0 = blockIdx.x * 64;
  f16* S = S0 + ((size_t)b * L + q0) * L;
  float* D = D0 + (size_t)b * L * L;
  const int tid = threadIdx.x;
  const int r = tid >> 3, seg = tid & 7;
  f16* src = S + (size_t)r * L;
  // pass 1a: row max (streams HBM; 8 lanes/row read 256B contiguous)
  float mx = -3.0e38f;
  for (int i = 0; i < L; i += 128) {
    const f16* c = src + i + seg * 16;
    f16x8 a = *(const f16x8*)c;
    f16x8 d = *(const f16x8*)(c + 8);
#pragma unroll
    for (int j = 0; j < 8; ++j) mx = fmaxf(mx, fmaxf((float)a[j], (float)d[j]));
  }
  mx = fmaxf(mx, __shfl_xor(mx, 1));
  mx = fmaxf(mx, __shfl_xor(mx, 2));
  mx = fmaxf(mx, __shfl_xor(mx, 4));
  // pass 1b: sum of exp (L2-hot re-read)
  float sum = 0.f;
  for (int i = 0; i < L; i += 128) {
    const f16* c = src + i + seg * 16;
    f16x8 a = *(const f16x8*)c;
    f16x8 d = *(const f16x8*)(c + 8);
#pragma unroll
    for (int j = 0; j < 8; ++j)
      sum += __expf((float)a[j] - mx) + __expf((float)d[j] - mx);
  }
  sum += __shfl_xor(sum, 1);
  sum += __shfl_xor(sum, 2);
  sum += __shfl_xor(sum, 4);
  const float inv = 1.f / sum;
  // pass 2: normalize; write p' f16 (in place, xPSCALE) + f32 transposed tiles
  for (int mm = 0; mm < L; mm += 64) {
    f16* c = src + mm + seg * 8;
    f16x8 a = *(const f16x8*)c;
    float y[8];
    f16x8 o;
#pragma unroll
    for (int j = 0; j < 8; ++j) {
      y[j] = __expf((float)a[j] - mx) * inv;
      o[j] = (f16)(y[j] * PSCALE);
      tile[seg * 8 + j][r] = y[j];
    }
    *(f16x8*)c = o;
    __syncthreads();
    // write D rows mm..mm+63: thread t -> row mm+(t>>3), cols (t&7)*8..+8
    float* dp = D + (size_t)(mm + (tid >> 3)) * L + q0 + (tid & 7) * 8;
    float4 w0, w1;
    w0.x = tile[tid >> 3][(tid & 7) * 8 + 0];
    w0.y = tile[tid >> 3][(tid & 7) * 8 + 1];
    w0.z = tile[tid >> 3][(tid & 7) * 8 + 2];
    w0.w = tile[tid >> 3][(tid & 7) * 8 + 3];
    w1.x = tile[tid >> 3][(tid & 7) * 8 + 4];
    w1.y = tile[tid >> 3][(tid & 7) * 8 + 5];
    w1.z = tile[tid >> 3][(tid & 7) * 8 + 6];
    w1.w = tile[tid >> 3][(tid & 7) * 8 + 7];
    *(float4*)dp = w0;
    *(float4*)(dp + 4) = w1;
    __syncthreads();
  }
}

// ---------------- fallback-path kernels (proven round-1) ----------------
__global__ __launch_bounds__(256)
void k_softmax(f16* __restrict__ S) {
  const size_t rowbase = (size_t)blockIdx.x * L;
  const int tid = threadIdx.x, ln = tid & 63, wv = tid >> 6;
  f16* p = S + rowbase + tid * 16;
  f16x8 v0 = *(const f16x8*)p;
  f16x8 v1 = *(const f16x8*)(p + 8);
  float x[16];
#pragma unroll
  for (int j = 0; j < 8; ++j) { x[j] = (float)v0[j]; x[8 + j] = (float)v1[j]; }
  float m = -3.0e38f;
#pragma unroll
  for (int j = 0; j < 16; ++j) m = fmaxf(m, x[j]);
#pragma unroll
  for (int off = 1; off < 64; off <<= 1) m = fmaxf(m, __shfl_xor(m, off));
  __shared__ float redm[4], reds[4];
  if (ln == 0) redm[wv] = m;
  __syncthreads();
  m = fmaxf(fmaxf(redm[0], redm[1]), fmaxf(redm[2], redm[3]));
  float s = 0.f;
#pragma unroll
  for (int j = 0; j < 16; ++j) { x[j] = __expf(x[j] - m); s += x[j]; }
#pragma unroll
  for (int off = 1; off < 64; off <<= 1) s += __shfl_xor(s, off);
  if (ln == 0) reds[wv] = s;
  __syncthreads();
  s = (reds[0] + reds[1]) + (reds[2] + reds[3]);
  const float k = PSCALE / s;
#pragma unroll
  for (int j = 0; j < 8; ++j) { v0[j] = (f16)(x[j] * k); v1[j] = (f16)(x[8 + j] * k); }
  *(f16x8*)p = v0;
  *(f16x8*)(p + 8) = v1;
}

__global__ __launch_bounds__(256)
void k_tr_out(const f16* __restrict__ src, float* __restrict__ dst, float scale) {
  __shared__ float tile[64][65];
  const int m0 = blockIdx.x * 64, q0 = blockIdx.y * 64;
  const int tid = threadIdx.x;
  const int r = tid >> 2, c4 = (tid & 3) * 16;
  const f16* sp = src + (size_t)(q0 + r) * L + m0 + c4;
  f16x8 a = *(const f16x8*)sp;
  f16x8 b = *(const f16x8*)(sp + 8);
#pragma unroll
  for (int j = 0; j < 8; ++j) {
    tile[c4 + j][r] = (float)a[j] * scale;
    tile[c4 + 8 + j][r] = (float)b[j] * scale;
  }
  __syncthreads();
  float* dp = dst + (size_t)(m0 + r) * L + q0 + c4;
#pragma unroll
  for (int g = 0; g < 4; ++g) {
    float4 w;
    w.x = tile[r][c4 + 4 * g + 0];
    w.y = tile[r][c4 + 4 * g + 1];
    w.z = tile[r][c4 + 4 * g + 2];
    w.w = tile[r][c4 + 4 * g + 3];
    *(float4*)(dp + 4 * g) = w;
  }
}

extern "C" void kernel_launch(void* const* d_in, const int* in_sizes, int n_in,
                              void* d_out, int out_size, void* d_ws, size_t ws_size,
                              hipStream_t stream) {
  const float* m_k = (const float*)d_in[0];
  const float* m_v = (const float*)d_in[1];
  const float* q_k = (const float*)d_in[2];
  char* ws = (char*)d_ws;
  float* memOut = (float*)d_out;                  // [B][Dv][L]
  float* pOut = memOut + (size_t)NBATCH * DV * L; // [B][L][L] f32
  const dim3 tb(32, 8, 1);
  const size_t LL = (size_t)L * L;

  const bool fused = ws_size >= ((size_t)152 << 20);
  if (fused) {
    // ws layout: [0,128M) p' f16 [B][Lq][Lm]; then qkT 4M, mkT 4M, mvh 16M
    f16* pp = (f16*)ws;
    f16* qkT = (f16*)(ws + ((size_t)128 << 20));
    f16* mkT = (f16*)(ws + ((size_t)132 << 20));
    f16* mvh = (f16*)(ws + ((size_t)136 << 20));
    k_tr_f32_f16<<<dim3(L / 32, DK / 32, NBATCH), tb, 0, stream>>>(q_k, qkT, DK, L);
    k_tr_f32_f16<<<dim3(L / 32, DK / 32, NBATCH), tb, 0, stream>>>(m_k, mkT, DK, L);
    k_cvt_f16<<<2048, 256, 0, stream>>>((const float4*)m_v, (f16x4*)mvh,
                                        NBATCH * DV * L / 4);
    // S'[q][m] raw scores (f16) into ws
    k_gemm_bt<true><<<dim3(L / 128, L / 128, NBATCH), 256, 0, stream>>>(
        qkT, mkT, (void*)pp, L, L, DK, 0.08838834764831845f);
    // fused softmax + f32-transpose: writes p' (ws, xPSCALE) and p (d_out)
    k_smtr<<<dim3(L / 64, NBATCH), 512, 0, stream>>>(pp, pOut);
    // mem[v][q] = sum_m mv[v][m] * p'[q][m] / PSCALE
    k_gemm_bt<false><<<dim3(L / 128, DV / 128, NBATCH), 256, 0, stream>>>(
        mvh, pp, (void*)memOut, DV, L, L, 1.f / PSCALE);
  } else {
    // proven round-1 path (p' overlaid on upper half of pOut + batch-3 bounce)
    f16* bounce = (f16*)ws;                      // 32 MiB
    f16* qkT = (f16*)(ws + ((size_t)32 << 20));  // 4 MiB
    f16* mkT = (f16*)(ws + ((size_t)36 << 20));  // 4 MiB
    f16* mvh = (f16*)(ws + ((size_t)40 << 20));  // 16 MiB
    f16* pp = (f16*)(pOut + NBATCH * LL / 2);    // upper half of pOut
    k_tr_f32_f16<<<dim3(L / 32, DK / 32, NBATCH), tb, 0, stream>>>(q_k, qkT, DK, L);
    k_tr_f32_f16<<<dim3(L / 32, DK / 32, NBATCH), tb, 0, stream>>>(m_k, mkT, DK, L);
    k_cvt_f16<<<2048, 256, 0, stream>>>((const float4*)m_v, (f16x4*)mvh,
                                        NBATCH * DV * L / 4);
    k_gemm_bt<true><<<dim3(L / 128, L / 128, NBATCH), 256, 0, stream>>>(
        qkT, mkT, (void*)pp, L, L, DK, 0.08838834764831845f);
    k_softmax<<<NBATCH * L, 256, 0, stream>>>(pp);
    hipMemcpyAsync(bounce, pp + 3 * LL, LL * sizeof(f16),
                   hipMemcpyDeviceToDevice, stream);
    k_gemm_bt<false><<<dim3(L / 128, DV / 128, NBATCH), 256, 0, stream>>>(
        mvh, pp, (void*)memOut, DV, L, L, 1.f / PSCALE);
    for (int b = 0; b < NBATCH; ++b) {
      const f16* src = (b == 3) ? bounce : (pp + (size_t)b * LL);
      k_tr_out<<<dim3(L / 64, L / 64), 256, 0, stream>>>(
          src, pOut + (size_t)b * LL, 1.f / PSCALE);
    }
  }
  (void)in_sizes; (void)n_in; (void)out_size; (void)ws_size;
}

// Round 3
// 300.245 us; speedup vs baseline: 1.0723x; 1.0597x over previous
//
#include <hip/hip_runtime.h>
#include <hip/hip_fp16.h>
#include <math.h>

typedef _Float16 f16;
typedef __attribute__((ext_vector_type(4))) _Float16 f16x4;
typedef __attribute__((ext_vector_type(8))) _Float16 f16x8;
typedef __attribute__((ext_vector_type(4))) float f32x4;

static constexpr int NBATCH = 4, DK = 128, DV = 512, L = 4096;
static constexpr float PSCALE = 256.f; // keep p' out of fp16-denormal range

__device__ __forceinline__ void async16(const void* g, void* l) {
  __builtin_amdgcn_global_load_lds((const __attribute__((address_space(1))) void*)g,
                                   (__attribute__((address_space(3))) void*)l, 16, 0, 0);
}

// combined input transposes: z<4 -> q_k batch z, z>=4 -> m_k batch z-4
// [DK][L] f32 -> [L][DK] f16
__global__ void k_tr2(const float* __restrict__ qk, const float* __restrict__ mk,
                      f16* __restrict__ qkT, f16* __restrict__ mkT) {
  __shared__ float tile[32][33];
  const int z = blockIdx.z;
  const size_t bs = (size_t)DK * L;
  const float* inb = (z < 4 ? qk : mk) + (size_t)(z & 3) * bs;
  f16* outb = (z < 4 ? qkT : mkT) + (size_t)(z & 3) * bs;
  const int c0 = blockIdx.x * 32, r0 = blockIdx.y * 32;
  const int tx = threadIdx.x, ty = threadIdx.y;
#pragma unroll
  for (int i = 0; i < 32; i += 8)
    tile[ty + i][tx] = inb[(size_t)(r0 + ty + i) * L + (c0 + tx)];
  __syncthreads();
#pragma unroll
  for (int i = 0; i < 32; i += 8)
    outb[(size_t)(c0 + ty + i) * DK + (r0 + tx)] = (f16)tile[tx][ty + i];
}

__global__ void k_cvt_f16(const float4* __restrict__ in, f16x4* __restrict__ out, int n4) {
  int i = blockIdx.x * blockDim.x + threadIdx.x;
  const int st = gridDim.x * blockDim.x;
  for (; i < n4; i += st) {
    float4 v = in[i];
    f16x4 o;
    o.x = (f16)v.x; o.y = (f16)v.y; o.z = (f16)v.z; o.w = (f16)v.w;
    out[i] = o;
  }
}

// C[z][row][col] = oscale * sum_k A[z][row][k] * B[z][col][k]
// A:[M][K] f16 row-major, B:[N][K] f16 row-major (both K-contiguous).
// 128x128 tile, BK=64, 4 waves (2x2), global_load_lds + XOR-source-swizzle.
// MODE 0 (QK): f16 out, T1 swizzle, per-block row expsum partials (no-max).
// MODE 1 (PV): f32 out, XCD-chunked + by-fastest mapping (B-panel L2 reuse).
template<int MODE>
__global__ __launch_bounds__(256, 2)
void k_gemm(const f16* __restrict__ A, const f16* __restrict__ B,
            void* __restrict__ C, float* __restrict__ partial,
            int M, int N, int K, float oscale) {
  constexpr int BK = 64;
  __shared__ __align__(16) f16 As[128 * BK];
  __shared__ __align__(16) f16 Bs[128 * BK];
  __shared__ float sums[128];
  const int z = blockIdx.z;
  int bx = blockIdx.x, by = blockIdx.y;
  {
    const int n = gridDim.x * gridDim.y;
    const int id = bx + gridDim.x * by;
    const int id2 = (id & 7) * (n >> 3) + (id >> 3); // XCD chunk (n%8==0)
    if (MODE == 0) { bx = id2 % gridDim.x; by = id2 / gridDim.x; }
    else           { by = id2 % gridDim.y; bx = id2 / gridDim.y; }
  }
  const f16* Ab = A + (size_t)z * M * K;
  const f16* Bbp = B + (size_t)z * N * K;
  const int row0 = by * 128, col0 = bx * 128;
  const int tid = threadIdx.x, lane = tid & 63, wv = tid >> 6;
  const int wr = wv >> 1, wc = wv & 1;
  f32x4 acc[4][4] = {};
  const int srow = wv * 32 + (lane >> 3);
  const int sc = (lane & 7) ^ (lane >> 3); // source chunk pre-swizzle
  const f16* aSrc = Ab + (size_t)(row0 + srow) * K + sc * 8;
  const f16* bSrc = Bbp + (size_t)(col0 + srow) * K + sc * 8;
  f16* aDst = &As[(wv * 32) * BK];
  f16* bDst = &Bs[(wv * 32) * BK];

  for (int k0 = 0; k0 < K; k0 += BK) {
    __syncthreads();
#pragma unroll
    for (int j = 0; j < 4; ++j) {
      async16(aSrc + (size_t)(j * 8) * K + k0, aDst + (j * 8) * BK);
      async16(bSrc + (size_t)(j * 8) * K + k0, bDst + (j * 8) * BK);
    }
    __syncthreads();
#pragma unroll
    for (int kk = 0; kk < BK / 32; ++kk) {
      const int cx = ((kk * 4 + (lane >> 4)) ^ (lane & 7)) * 8;
      f16x8 av[4], bv[4];
#pragma unroll
      for (int i = 0; i < 4; ++i) {
        av[i] = *(const f16x8*)&As[(wr * 64 + i * 16 + (lane & 15)) * BK + cx];
        bv[i] = *(const f16x8*)&Bs[(wc * 64 + i * 16 + (lane & 15)) * BK + cx];
      }
#pragma unroll
      for (int i = 0; i < 4; ++i)
#pragma unroll
        for (int j = 0; j < 4; ++j)
          acc[i][j] = __builtin_amdgcn_mfma_f32_16x16x32_f16(av[i], bv[j], acc[i][j], 0, 0, 0);
    }
  }
  // C/D layout: col = lane&15, row = (lane>>4)*4 + t
  const size_t cb = (size_t)z * M * N;
  const int er = (lane >> 4) * 4, ec = lane & 15;
#pragma unroll
  for (int i = 0; i < 4; ++i) {
    const int r = row0 + wr * 64 + i * 16 + er;
#pragma unroll
    for (int j = 0; j < 4; ++j) {
      const int c = col0 + wc * 64 + j * 16 + ec;
#pragma unroll
      for (int t = 0; t < 4; ++t) {
        const float v = acc[i][j][t] * oscale;
        if (MODE == 0) ((f16*)C)[cb + (size_t)(r + t) * N + c] = (f16)v;
        else          ((float*)C)[cb + (size_t)(r + t) * N + c] = v;
      }
    }
  }
  if (MODE == 0) {
    // per-row partial sum of exp over this block's 128 cols (no-max softmax)
    float rp[16];
#pragma unroll
    for (int i = 0; i < 4; ++i)
#pragma unroll
      for (int t = 0; t < 4; ++t) {
        float s_ = 0.f;
#pragma unroll
        for (int j = 0; j < 4; ++j) s_ += __expf(acc[i][j][t] * oscale);
        rp[i * 4 + t] = s_;
      }
#pragma unroll
    for (int u = 0; u < 16; ++u) {
      rp[u] += __shfl_xor(rp[u], 1);
      rp[u] += __shfl_xor(rp[u], 2);
      rp[u] += __shfl_xor(rp[u], 4);
      rp[u] += __shfl_xor(rp[u], 8);
    }
    // combine the two col-waves (wc) per row: exactly 2 addends -> deterministic
    if (wc == 1 && (lane & 15) == 0) {
#pragma unroll
      for (int i = 0; i < 4; ++i)
#pragma unroll
        for (int t = 0; t < 4; ++t)
          sums[wr * 64 + i * 16 + (lane >> 4) * 4 + t] = rp[i * 4 + t];
    }
    __syncthreads();
    if (wc == 0 && (lane & 15) == 0) {
#pragma unroll
      for (int i = 0; i < 4; ++i)
#pragma unroll
        for (int t = 0; t < 4; ++t) {
          const int r = wr * 64 + i * 16 + (lane >> 4) * 4 + t;
          partial[((size_t)z * gridDim.x + bx) * L + row0 + r] = rp[i * 4 + t] + sums[r];
        }
    }
  }
}

// rowinv[z][q] = 1 / sum_bx partial[z][bx][q]
__global__ __launch_bounds__(256)
void k_rowsum(const float* __restrict__ partial, float* __restrict__ rowinv) {
  const int qi = blockIdx.x * 256 + threadIdx.x; // 0..16383
  const int z = qi >> 12, q = qi & 4095;
  float s = 0.f;
#pragma unroll
  for (int bx = 0; bx < 32; ++bx) s += partial[((size_t)z * 32 + bx) * L + q];
  rowinv[qi] = 1.f / s;
}

// single pass: read raw S'[q][m] f16, y = exp(s)*rowinv[q];
// write p' = y*PSCALE f16 in place + p f32 transposed [m][q].
__global__ __launch_bounds__(256)
void k_smtr2(f16* __restrict__ S0, float* __restrict__ D0,
             const float* __restrict__ rowinv) {
  __shared__ float tile[64][65];
  const int b = blockIdx.z;
  const int q0 = blockIdx.x * 64, m0 = blockIdx.y * 64;
  f16* S = S0 + (size_t)b * L * L;
  float* D = D0 + (size_t)b * L * L;
  const int tid = threadIdx.x;
  const int r = tid >> 2, c4 = (tid & 3) * 16;
  f16* sp = S + (size_t)(q0 + r) * L + m0 + c4;
  const float inv = rowinv[b * L + q0 + r];
  f16x8 a = *(const f16x8*)sp;
  f16x8 c = *(const f16x8*)(sp + 8);
  f16x8 oa, oc;
#pragma unroll
  for (int j = 0; j < 8; ++j) {
    const float ya = __expf((float)a[j]) * inv;
    const float yc = __expf((float)c[j]) * inv;
    oa[j] = (f16)(ya * PSCALE);
    oc[j] = (f16)(yc * PSCALE);
    tile[c4 + j][r] = ya;
    tile[c4 + 8 + j][r] = yc;
  }
  *(f16x8*)sp = oa;
  *(f16x8*)(sp + 8) = oc;
  __syncthreads();
  float* dp = D + (size_t)(m0 + r) * L + q0 + c4;
#pragma unroll
  for (int g = 0; g < 4; ++g) {
    float4 w;
    w.x = tile[r][c4 + 4 * g + 0];
    w.y = tile[r][c4 + 4 * g + 1];
    w.z = tile[r][c4 + 4 * g + 2];
    w.w = tile[r][c4 + 4 * g + 3];
    *(float4*)(dp + 4 * g) = w;
  }
}

// ---------------- fallback-path kernels (proven round-1) ----------------
template<bool OUT_F16>
__global__ __launch_bounds__(256, 2)
void k_gemm_bt(const f16* __restrict__ A, const f16* __restrict__ B,
               void* __restrict__ C, int M, int N, int K, float oscale) {
  constexpr int BK = 64;
  __shared__ __align__(16) f16 As[128 * BK];
  __shared__ __align__(16) f16 Bs[128 * BK];
  const int z = blockIdx.z;
  const f16* Ab = A + (size_t)z * M * K;
  const f16* Bbp = B + (size_t)z * N * K;
  const int row0 = blockIdx.y * 128, col0 = blockIdx.x * 128;
  const int tid = threadIdx.x, lane = tid & 63, wv = tid >> 6;
  const int wr = wv >> 1, wc = wv & 1;
  f32x4 acc[4][4] = {};
  const int srow = wv * 32 + (lane >> 3);
  const int sc = (lane & 7) ^ (lane >> 3);
  const f16* aSrc = Ab + (size_t)(row0 + srow) * K + sc * 8;
  const f16* bSrc = Bbp + (size_t)(col0 + srow) * K + sc * 8;
  f16* aDst = &As[(wv * 32) * BK];
  f16* bDst = &Bs[(wv * 32) * BK];
  for (int k0 = 0; k0 < K; k0 += BK) {
    __syncthreads();
#pragma unroll
    for (int j = 0; j < 4; ++j) {
      async16(aSrc + (size_t)(j * 8) * K + k0, aDst + (j * 8) * BK);
      async16(bSrc + (size_t)(j * 8) * K + k0, bDst + (j * 8) * BK);
    }
    __syncthreads();
#pragma unroll
    for (int kk = 0; kk < BK / 32; ++kk) {
      const int cx = ((kk * 4 + (lane >> 4)) ^ (lane & 7)) * 8;
      f16x8 av[4], bv[4];
#pragma unroll
      for (int i = 0; i < 4; ++i) {
        av[i] = *(const f16x8*)&As[(wr * 64 + i * 16 + (lane & 15)) * BK + cx];
        bv[i] = *(const f16x8*)&Bs[(wc * 64 + i * 16 + (lane & 15)) * BK + cx];
      }
#pragma unroll
      for (int i = 0; i < 4; ++i)
#pragma unroll
        for (int j = 0; j < 4; ++j)
          acc[i][j] = __builtin_amdgcn_mfma_f32_16x16x32_f16(av[i], bv[j], acc[i][j], 0, 0, 0);
    }
  }
  const size_t cb = (size_t)z * M * N;
  const int er = (lane >> 4) * 4, ec = lane & 15;
#pragma unroll
  for (int i = 0; i < 4; ++i) {
    const int r = row0 + wr * 64 + i * 16 + er;
#pragma unroll
    for (int j = 0; j < 4; ++j) {
      const int c = col0 + wc * 64 + j * 16 + ec;
#pragma unroll
      for (int t = 0; t < 4; ++t) {
        const float v = acc[i][j][t] * oscale;
        if (OUT_F16) ((f16*)C)[cb + (size_t)(r + t) * N + c] = (f16)v;
        else        ((float*)C)[cb + (size_t)(r + t) * N + c] = v;
      }
    }
  }
}

__global__ __launch_bounds__(256)
void k_softmax(f16* __restrict__ S) {
  const size_t rowbase = (size_t)blockIdx.x * L;
  const int tid = threadIdx.x, ln = tid & 63, wv = tid >> 6;
  f16* p = S + rowbase + tid * 16;
  f16x8 v0 = *(const f16x8*)p;
  f16x8 v1 = *(const f16x8*)(p + 8);
  float x[16];
#pragma unroll
  for (int j = 0; j < 8; ++j) { x[j] = (float)v0[j]; x[8 + j] = (float)v1[j]; }
  float m = -3.0e38f;
#pragma unroll
  for (int j = 0; j < 16; ++j) m = fmaxf(m, x[j]);
#pragma unroll
  for (int off = 1; off < 64; off <<= 1) m = fmaxf(m, __shfl_xor(m, off));
  __shared__ float redm[4], reds[4];
  if (ln == 0) redm[wv] = m;
  __syncthreads();
  m = fmaxf(fmaxf(redm[0], redm[1]), fmaxf(redm[2], redm[3]));
  float s = 0.f;
#pragma unroll
  for (int j = 0; j < 16; ++j) { x[j] = __expf(x[j] - m); s += x[j]; }
#pragma unroll
  for (int off = 1; off < 64; off <<= 1) s += __shfl_xor(s, off);
  if (ln == 0) reds[wv] = s;
  __syncthreads();
  s = (reds[0] + reds[1]) + (reds[2] + reds[3]);
  const float k = PSCALE / s;
#pragma unroll
  for (int j = 0; j < 8; ++j) { v0[j] = (f16)(x[j] * k); v1[j] = (f16)(x[8 + j] * k); }
  *(f16x8*)p = v0;
  *(f16x8*)(p + 8) = v1;
}

__global__ __launch_bounds__(256)
void k_tr_out(const f16* __restrict__ src, float* __restrict__ dst, float scale) {
  __shared__ float tile[64][65];
  const int m0 = blockIdx.x * 64, q0 = blockIdx.y * 64;
  const int tid = threadIdx.x;
  const int r = tid >> 2, c4 = (tid & 3) * 16;
  const f16* sp = src + (size_t)(q0 + r) * L + m0 + c4;
  f16x8 a = *(const f16x8*)sp;
  f16x8 b = *(const f16x8*)(sp + 8);
#pragma unroll
  for (int j = 0; j < 8; ++j) {
    tile[c4 + j][r] = (float)a[j] * scale;
    tile[c4 + 8 + j][r] = (float)b[j] * scale;
  }
  __syncthreads();
  float* dp = dst + (size_t)(m0 + r) * L + q0 + c4;
#pragma unroll
  for (int g = 0; g < 4; ++g) {
    float4 w;
    w.x = tile[r][c4 + 4 * g + 0];
    w.y = tile[r][c4 + 4 * g + 1];
    w.z = tile[r][c4 + 4 * g + 2];
    w.w = tile[r][c4 + 4 * g + 3];
    *(float4*)(dp + 4 * g) = w;
  }
}

extern "C" void kernel_launch(void* const* d_in, const int* in_sizes, int n_in,
                              void* d_out, int out_size, void* d_ws, size_t ws_size,
                              hipStream_t stream) {
  const float* m_k = (const float*)d_in[0];
  const float* m_v = (const float*)d_in[1];
  const float* q_k = (const float*)d_in[2];
  char* ws = (char*)d_ws;
  float* memOut = (float*)d_out;                  // [B][Dv][L]
  float* pOut = memOut + (size_t)NBATCH * DV * L; // [B][L][L] f32
  const size_t LL = (size_t)L * L;

  const bool fused = ws_size >= ((size_t)160 << 20);
  if (fused) {
    f16* pp = (f16*)ws;                                   // 128 MiB S'/p'
    float* partial = (float*)(ws + ((size_t)128 << 20));  // 2 MiB
    float* rowinv = (float*)(ws + ((size_t)130 << 20));   // 64 KiB
    f16* qkT = (f16*)(ws + ((size_t)131 << 20));          // 4 MiB
    f16* mkT = (f16*)(ws + ((size_t)135 << 20));          // 4 MiB
    f16* mvh = (f16*)(ws + ((size_t)139 << 20));          // 16 MiB
    k_tr2<<<dim3(L / 32, DK / 32, 8), dim3(32, 8), 0, stream>>>(q_k, m_k, qkT, mkT);
    k_cvt_f16<<<2048, 256, 0, stream>>>((const float4*)m_v, (f16x4*)mvh,
                                        NBATCH * DV * L / 4);
    // S'[q][m] raw (f16) + per-block row expsum partials
    k_gemm<0><<<dim3(L / 128, L / 128, NBATCH), 256, 0, stream>>>(
        qkT, mkT, (void*)pp, partial, L, L, DK, 0.08838834764831845f);
    k_rowsum<<<NBATCH * L / 256, 256, 0, stream>>>(partial, rowinv);
    // single pass: p' f16 in place + f32 transposed p
    k_smtr2<<<dim3(L / 64, L / 64, NBATCH), 256, 0, stream>>>(pp, pOut, rowinv);
    // mem[v][q] = sum_m mv[v][m] * p'[q][m] / PSCALE
    k_gemm<1><<<dim3(L / 128, DV / 128, NBATCH), 256, 0, stream>>>(
        mvh, pp, (void*)memOut, nullptr, DV, L, L, 1.f / PSCALE);
  } else {
    // proven round-1 path
    f16* bounce = (f16*)ws;
    f16* qkT = (f16*)(ws + ((size_t)32 << 20));
    f16* mkT = (f16*)(ws + ((size_t)36 << 20));
    f16* mvh = (f16*)(ws + ((size_t)40 << 20));
    f16* pp = (f16*)(pOut + NBATCH * LL / 2);
    k_tr2<<<dim3(L / 32, DK / 32, 8), dim3(32, 8), 0, stream>>>(q_k, m_k, qkT, mkT);
    k_cvt_f16<<<2048, 256, 0, stream>>>((const float4*)m_v, (f16x4*)mvh,
                                        NBATCH * DV * L / 4);
    k_gemm_bt<true><<<dim3(L / 128, L / 128, NBATCH), 256, 0, stream>>>(
        qkT, mkT, (void*)pp, L, L, DK, 0.08838834764831845f);
    k_softmax<<<NBATCH * L, 256, 0, stream>>>(pp);
    hipMemcpyAsync(bounce, pp + 3 * LL, LL * sizeof(f16),
                   hipMemcpyDeviceToDevice, stream);
    k_gemm_bt<false><<<dim3(L / 128, DV / 128, NBATCH), 256, 0, stream>>>(
        mvh, pp, (void*)memOut, DV, L, L, 1.f / PSCALE);
    for (int b = 0; b < NBATCH; ++b) {
      const f16* src = (b == 3) ? bounce : (pp + (size_t)b * LL);
      k_tr_out<<<dim3(L / 64, L / 64), 256, 0, stream>>>(
          src, pOut + (size_t)b * LL, 1.f / PSCALE);
    }
  }
  (void)in_sizes; (void)n_in; (void)out_size; (void)ws_size;
}

// Round 4
// 269.428 us; speedup vs baseline: 1.1950x; 1.1144x over previous
//
#include <hip/hip_runtime.h>
#include <hip/hip_fp16.h>
#include <math.h>

typedef _Float16 f16;
typedef __attribute__((ext_vector_type(4))) _Float16 f16x4;
typedef __attribute__((ext_vector_type(8))) _Float16 f16x8;
typedef __attribute__((ext_vector_type(4))) float f32x4;

static constexpr int NBATCH = 4, DK = 128, DV = 512, L = 4096;
static constexpr float PSCALE = 256.f; // fallback path only

__device__ __forceinline__ void async16(const void* g, void* l) {
  __builtin_amdgcn_global_load_lds((const __attribute__((address_space(1))) void*)g,
                                   (__attribute__((address_space(3))) void*)l, 16, 0, 0);
}

// combined input transposes: z<4 -> q_k batch z, z>=4 -> m_k batch z-4
// [DK][L] f32 -> [L][DK] f16
__global__ void k_tr2(const float* __restrict__ qk, const float* __restrict__ mk,
                      f16* __restrict__ qkT, f16* __restrict__ mkT) {
  __shared__ float tile[32][33];
  const int z = blockIdx.z;
  const size_t bs = (size_t)DK * L;
  const float* inb = (z < 4 ? qk : mk) + (size_t)(z & 3) * bs;
  f16* outb = (z < 4 ? qkT : mkT) + (size_t)(z & 3) * bs;
  const int c0 = blockIdx.x * 32, r0 = blockIdx.y * 32;
  const int tx = threadIdx.x, ty = threadIdx.y;
#pragma unroll
  for (int i = 0; i < 32; i += 8)
    tile[ty + i][tx] = inb[(size_t)(r0 + ty + i) * L + (c0 + tx)];
  __syncthreads();
#pragma unroll
  for (int i = 0; i < 32; i += 8)
    outb[(size_t)(c0 + ty + i) * DK + (r0 + tx)] = (f16)tile[tx][ty + i];
}

__global__ void k_cvt_f16(const float4* __restrict__ in, f16x4* __restrict__ out, int n4) {
  int i = blockIdx.x * blockDim.x + threadIdx.x;
  const int st = gridDim.x * blockDim.x;
  for (; i < n4; i += st) {
    float4 v = in[i];
    f16x4 o;
    o.x = (f16)v.x; o.y = (f16)v.y; o.z = (f16)v.z; o.w = (f16)v.w;
    out[i] = o;
  }
}

// C[z][row][col] = f(sum_k A[z][row][k] * B[z][col][k])
// A:[M][K] f16 row-major, B:[N][K] f16 row-major (both K-contiguous).
// 128x128 tile, BK=64, 4 waves (2x2), global_load_lds + XOR-source-swizzle.
// MODE 0 (QK): writes e' = exp(s*oscale) f16 + per-block row expsum partials.
// MODE 1 (PV): f32 out scaled by aux[col] (rowinv); by-fastest XCD chunking.
template<int MODE>
__global__ __launch_bounds__(256, 2)
void k_gemm(const f16* __restrict__ A, const f16* __restrict__ B,
            void* __restrict__ C, float* __restrict__ aux,
            int M, int N, int K, float oscale) {
  constexpr int BK = 64;
  __shared__ __align__(16) f16 As[128 * BK];
  __shared__ __align__(16) f16 Bs[128 * BK];
  __shared__ float sums[128];
  const int z = blockIdx.z;
  int bx = blockIdx.x, by = blockIdx.y;
  {
    const int n = gridDim.x * gridDim.y;
    const int id = bx + gridDim.x * by;
    const int id2 = (id & 7) * (n >> 3) + (id >> 3); // XCD chunk (n%8==0)
    if (MODE == 0) { bx = id2 % gridDim.x; by = id2 / gridDim.x; }
    else           { by = id2 % gridDim.y; bx = id2 / gridDim.y; }
  }
  const f16* Ab = A + (size_t)z * M * K;
  const f16* Bbp = B + (size_t)z * N * K;
  const int row0 = by * 128, col0 = bx * 128;
  const int tid = threadIdx.x, lane = tid & 63, wv = tid >> 6;
  const int wr = wv >> 1, wc = wv & 1;
  f32x4 acc[4][4] = {};
  const int srow = wv * 32 + (lane >> 3);
  const int sc = (lane & 7) ^ (lane >> 3); // source chunk pre-swizzle
  const f16* aSrc = Ab + (size_t)(row0 + srow) * K + sc * 8;
  const f16* bSrc = Bbp + (size_t)(col0 + srow) * K + sc * 8;
  f16* aDst = &As[(wv * 32) * BK];
  f16* bDst = &Bs[(wv * 32) * BK];

  for (int k0 = 0; k0 < K; k0 += BK) {
    __syncthreads();
#pragma unroll
    for (int j = 0; j < 4; ++j) {
      async16(aSrc + (size_t)(j * 8) * K + k0, aDst + (j * 8) * BK);
      async16(bSrc + (size_t)(j * 8) * K + k0, bDst + (j * 8) * BK);
    }
    __syncthreads();
#pragma unroll
    for (int kk = 0; kk < BK / 32; ++kk) {
      const int cx = ((kk * 4 + (lane >> 4)) ^ (lane & 7)) * 8;
      f16x8 av[4], bv[4];
#pragma unroll
      for (int i = 0; i < 4; ++i) {
        av[i] = *(const f16x8*)&As[(wr * 64 + i * 16 + (lane & 15)) * BK + cx];
        bv[i] = *(const f16x8*)&Bs[(wc * 64 + i * 16 + (lane & 15)) * BK + cx];
      }
#pragma unroll
      for (int i = 0; i < 4; ++i)
#pragma unroll
        for (int j = 0; j < 4; ++j)
          acc[i][j] = __builtin_amdgcn_mfma_f32_16x16x32_f16(av[i], bv[j], acc[i][j], 0, 0, 0);
    }
  }
  // C/D layout: col = lane&15, row = (lane>>4)*4 + t
  const size_t cb = (size_t)z * M * N;
  const int er = (lane >> 4) * 4, ec = lane & 15;
  if (MODE == 0) {
    // e' = exp(acc*oscale) f16 out + per-row expsum partials (no-max softmax)
    float rp[16];
#pragma unroll
    for (int u = 0; u < 16; ++u) rp[u] = 0.f;
#pragma unroll
    for (int i = 0; i < 4; ++i) {
      const int r = row0 + wr * 64 + i * 16 + er;
#pragma unroll
      for (int j = 0; j < 4; ++j) {
        const int c = col0 + wc * 64 + j * 16 + ec;
#pragma unroll
        for (int t = 0; t < 4; ++t) {
          const float e = __expf(acc[i][j][t] * oscale);
          ((f16*)C)[cb + (size_t)(r + t) * N + c] = (f16)e;
          rp[i * 4 + t] += e;
        }
      }
    }
#pragma unroll
    for (int u = 0; u < 16; ++u) {
      rp[u] += __shfl_xor(rp[u], 1);
      rp[u] += __shfl_xor(rp[u], 2);
      rp[u] += __shfl_xor(rp[u], 4);
      rp[u] += __shfl_xor(rp[u], 8);
    }
    // combine the two col-waves (wc): exactly 2 addends -> deterministic
    if (wc == 1 && (lane & 15) == 0) {
#pragma unroll
      for (int i = 0; i < 4; ++i)
#pragma unroll
        for (int t = 0; t < 4; ++t)
          sums[wr * 64 + i * 16 + (lane >> 4) * 4 + t] = rp[i * 4 + t];
    }
    __syncthreads();
    if (wc == 0 && (lane & 15) == 0) {
#pragma unroll
      for (int i = 0; i < 4; ++i)
#pragma unroll
        for (int t = 0; t < 4; ++t) {
          const int r = wr * 64 + i * 16 + (lane >> 4) * 4 + t;
          aux[((size_t)z * gridDim.x + bx) * L + row0 + r] = rp[i * 4 + t] + sums[r];
        }
    }
  } else {
    // PV: scale output columns by rowinv
    float rv[4];
#pragma unroll
    for (int j = 0; j < 4; ++j)
      rv[j] = aux[(size_t)z * L + col0 + wc * 64 + j * 16 + ec];
#pragma unroll
    for (int i = 0; i < 4; ++i) {
      const int r = row0 + wr * 64 + i * 16 + er;
#pragma unroll
      for (int j = 0; j < 4; ++j) {
        const int c = col0 + wc * 64 + j * 16 + ec;
#pragma unroll
        for (int t = 0; t < 4; ++t)
          ((float*)C)[cb + (size_t)(r + t) * N + c] = acc[i][j][t] * rv[j];
      }
    }
  }
}

// rowinv[z][q] = 1 / sum_bx partial[z][bx][q]
__global__ __launch_bounds__(256)
void k_rowsum(const float* __restrict__ partial, float* __restrict__ rowinv) {
  const int qi = blockIdx.x * 256 + threadIdx.x; // 0..16383
  const int z = qi >> 12, q = qi & 4095;
  float s = 0.f;
#pragma unroll
  for (int bx = 0; bx < 32; ++bx) s += partial[((size_t)z * 32 + bx) * L + q];
  rowinv[qi] = 1.f / s;
}

// p f32 [m][q] = e'[q][m] * rowinv[q]  (pure scale + transpose, single pass)
__global__ __launch_bounds__(256)
void k_smtr3(const f16* __restrict__ E0, float* __restrict__ D0,
             const float* __restrict__ rowinv) {
  __shared__ float tile[64][65];
  const int b = blockIdx.z;
  const int q0 = blockIdx.x * 64, m0 = blockIdx.y * 64;
  const f16* E = E0 + (size_t)b * L * L;
  float* D = D0 + (size_t)b * L * L;
  const int tid = threadIdx.x;
  const int r = tid >> 2, c4 = (tid & 3) * 16;
  const f16* sp = E + (size_t)(q0 + r) * L + m0 + c4;
  const float inv = rowinv[b * L + q0 + r];
  f16x8 a = *(const f16x8*)sp;
  f16x8 c = *(const f16x8*)(sp + 8);
#pragma unroll
  for (int j = 0; j < 8; ++j) {
    tile[c4 + j][r] = (float)a[j] * inv;
    tile[c4 + 8 + j][r] = (float)c[j] * inv;
  }
  __syncthreads();
  float* dp = D + (size_t)(m0 + r) * L + q0 + c4;
#pragma unroll
  for (int g = 0; g < 4; ++g) {
    float4 w;
    w.x = tile[r][c4 + 4 * g + 0];
    w.y = tile[r][c4 + 4 * g + 1];
    w.z = tile[r][c4 + 4 * g + 2];
    w.w = tile[r][c4 + 4 * g + 3];
    *(float4*)(dp + 4 * g) = w;
  }
}

// ---------------- fallback-path kernels (proven round-1) ----------------
template<bool OUT_F16>
__global__ __launch_bounds__(256, 2)
void k_gemm_bt(const f16* __restrict__ A, const f16* __restrict__ B,
               void* __restrict__ C, int M, int N, int K, float oscale) {
  constexpr int BK = 64;
  __shared__ __align__(16) f16 As[128 * BK];
  __shared__ __align__(16) f16 Bs[128 * BK];
  const int z = blockIdx.z;
  const f16* Ab = A + (size_t)z * M * K;
  const f16* Bbp = B + (size_t)z * N * K;
  const int row0 = blockIdx.y * 128, col0 = blockIdx.x * 128;
  const int tid = threadIdx.x, lane = tid & 63, wv = tid >> 6;
  const int wr = wv >> 1, wc = wv & 1;
  f32x4 acc[4][4] = {};
  const int srow = wv * 32 + (lane >> 3);
  const int sc = (lane & 7) ^ (lane >> 3);
  const f16* aSrc = Ab + (size_t)(row0 + srow) * K + sc * 8;
  const f16* bSrc = Bbp + (size_t)(col0 + srow) * K + sc * 8;
  f16* aDst = &As[(wv * 32) * BK];
  f16* bDst = &Bs[(wv * 32) * BK];
  for (int k0 = 0; k0 < K; k0 += BK) {
    __syncthreads();
#pragma unroll
    for (int j = 0; j < 4; ++j) {
      async16(aSrc + (size_t)(j * 8) * K + k0, aDst + (j * 8) * BK);
      async16(bSrc + (size_t)(j * 8) * K + k0, bDst + (j * 8) * BK);
    }
    __syncthreads();
#pragma unroll
    for (int kk = 0; kk < BK / 32; ++kk) {
      const int cx = ((kk * 4 + (lane >> 4)) ^ (lane & 7)) * 8;
      f16x8 av[4], bv[4];
#pragma unroll
      for (int i = 0; i < 4; ++i) {
        av[i] = *(const f16x8*)&As[(wr * 64 + i * 16 + (lane & 15)) * BK + cx];
        bv[i] = *(const f16x8*)&Bs[(wc * 64 + i * 16 + (lane & 15)) * BK + cx];
      }
#pragma unroll
      for (int i = 0; i < 4; ++i)
#pragma unroll
        for (int j = 0; j < 4; ++j)
          acc[i][j] = __builtin_amdgcn_mfma_f32_16x16x32_f16(av[i], bv[j], acc[i][j], 0, 0, 0);
    }
  }
  const size_t cb = (size_t)z * M * N;
  const int er = (lane >> 4) * 4, ec = lane & 15;
#pragma unroll
  for (int i = 0; i < 4; ++i) {
    const int r = row0 + wr * 64 + i * 16 + er;
#pragma unroll
    for (int j = 0; j < 4; ++j) {
      const int c = col0 + wc * 64 + j * 16 + ec;
#pragma unroll
      for (int t = 0; t < 4; ++t) {
        const float v = acc[i][j][t] * oscale;
        if (OUT_F16) ((f16*)C)[cb + (size_t)(r + t) * N + c] = (f16)v;
        else        ((float*)C)[cb + (size_t)(r + t) * N + c] = v;
      }
    }
  }
}

__global__ __launch_bounds__(256)
void k_softmax(f16* __restrict__ S) {
  const size_t rowbase = (size_t)blockIdx.x * L;
  const int tid = threadIdx.x, ln = tid & 63, wv = tid >> 6;
  f16* p = S + rowbase + tid * 16;
  f16x8 v0 = *(const f16x8*)p;
  f16x8 v1 = *(const f16x8*)(p + 8);
  float x[16];
#pragma unroll
  for (int j = 0; j < 8; ++j) { x[j] = (float)v0[j]; x[8 + j] = (float)v1[j]; }
  float m = -3.0e38f;
#pragma unroll
  for (int j = 0; j < 16; ++j) m = fmaxf(m, x[j]);
#pragma unroll
  for (int off = 1; off < 64; off <<= 1) m = fmaxf(m, __shfl_xor(m, off));
  __shared__ float redm[4], reds[4];
  if (ln == 0) redm[wv] = m;
  __syncthreads();
  m = fmaxf(fmaxf(redm[0], redm[1]), fmaxf(redm[2], redm[3]));
  float s = 0.f;
#pragma unroll
  for (int j = 0; j < 16; ++j) { x[j] = __expf(x[j] - m); s += x[j]; }
#pragma unroll
  for (int off = 1; off < 64; off <<= 1) s += __shfl_xor(s, off);
  if (ln == 0) reds[wv] = s;
  __syncthreads();
  s = (reds[0] + reds[1]) + (reds[2] + reds[3]);
  const float k = PSCALE / s;
#pragma unroll
  for (int j = 0; j < 8; ++j) { v0[j] = (f16)(x[j] * k); v1[j] = (f16)(x[8 + j] * k); }
  *(f16x8*)p = v0;
  *(f16x8*)(p + 8) = v1;
}

__global__ __launch_bounds__(256)
void k_tr_out(const f16* __restrict__ src, float* __restrict__ dst, float scale) {
  __shared__ float tile[64][65];
  const int m0 = blockIdx.x * 64, q0 = blockIdx.y * 64;
  const int tid = threadIdx.x;
  const int r = tid >> 2, c4 = (tid & 3) * 16;
  const f16* sp = src + (size_t)(q0 + r) * L + m0 + c4;
  f16x8 a = *(const f16x8*)sp;
  f16x8 b = *(const f16x8*)(sp + 8);
#pragma unroll
  for (int j = 0; j < 8; ++j) {
    tile[c4 + j][r] = (float)a[j] * scale;
    tile[c4 + 8 + j][r] = (float)b[j] * scale;
  }
  __syncthreads();
  float* dp = dst + (size_t)(m0 + r) * L + q0 + c4;
#pragma unroll
  for (int g = 0; g < 4; ++g) {
    float4 w;
    w.x = tile[r][c4 + 4 * g + 0];
    w.y = tile[r][c4 + 4 * g + 1];
    w.z = tile[r][c4 + 4 * g + 2];
    w.w = tile[r][c4 + 4 * g + 3];
    *(float4*)(dp + 4 * g) = w;
  }
}

extern "C" void kernel_launch(void* const* d_in, const int* in_sizes, int n_in,
                              void* d_out, int out_size, void* d_ws, size_t ws_size,
                              hipStream_t stream) {
  const float* m_k = (const float*)d_in[0];
  const float* m_v = (const float*)d_in[1];
  const float* q_k = (const float*)d_in[2];
  char* ws = (char*)d_ws;
  float* memOut = (float*)d_out;                  // [B][Dv][L]
  float* pOut = memOut + (size_t)NBATCH * DV * L; // [B][L][L] f32
  const size_t LL = (size_t)L * L;

  const bool fused = ws_size >= ((size_t)160 << 20);
  if (fused) {
    f16* pp = (f16*)ws;                                   // 128 MiB e'
    float* partial = (float*)(ws + ((size_t)128 << 20));  // 2 MiB
    float* rowinv = (float*)(ws + ((size_t)130 << 20));   // 64 KiB
    f16* qkT = (f16*)(ws + ((size_t)131 << 20));          // 4 MiB
    f16* mkT = (f16*)(ws + ((size_t)135 << 20));          // 4 MiB
    f16* mvh = (f16*)(ws + ((size_t)139 << 20));          // 16 MiB
    k_tr2<<<dim3(L / 32, DK / 32, 8), dim3(32, 8), 0, stream>>>(q_k, m_k, qkT, mkT);
    k_cvt_f16<<<2048, 256, 0, stream>>>((const float4*)m_v, (f16x4*)mvh,
                                        NBATCH * DV * L / 4);
    // e'[q][m] = exp(s) f16 + per-block row expsum partials
    k_gemm<0><<<dim3(L / 128, L / 128, NBATCH), 256, 0, stream>>>(
        qkT, mkT, (void*)pp, partial, L, L, DK, 0.08838834764831845f);
    k_rowsum<<<NBATCH * L / 256, 256, 0, stream>>>(partial, rowinv);
    // p f32 transposed = e' * rowinv (single streaming pass)
    k_smtr3<<<dim3(L / 64, L / 64, NBATCH), 256, 0, stream>>>(pp, pOut, rowinv);
    // mem[v][q] = rowinv[q] * sum_m mv[v][m] * e'[q][m]
    k_gemm<1><<<dim3(L / 128, DV / 128, NBATCH), 256, 0, stream>>>(
        mvh, pp, (void*)memOut, rowinv, DV, L, L, 1.f);
  } else {
    // proven round-1 path
    f16* bounce = (f16*)ws;
    f16* qkT = (f16*)(ws + ((size_t)32 << 20));
    f16* mkT = (f16*)(ws + ((size_t)36 << 20));
    f16* mvh = (f16*)(ws + ((size_t)40 << 20));
    f16* pp = (f16*)(pOut + NBATCH * LL / 2);
    k_tr2<<<dim3(L / 32, DK / 32, 8), dim3(32, 8), 0, stream>>>(q_k, m_k, qkT, mkT);
    k_cvt_f16<<<2048, 256, 0, stream>>>((const float4*)m_v, (f16x4*)mvh,
                                        NBATCH * DV * L / 4);
    k_gemm_bt<true><<<dim3(L / 128, L / 128, NBATCH), 256, 0, stream>>>(
        qkT, mkT, (void*)pp, L, L, DK, 0.08838834764831845f);
    k_softmax<<<NBATCH * L, 256, 0, stream>>>(pp);
    hipMemcpyAsync(bounce, pp + 3 * LL, LL * sizeof(f16),
                   hipMemcpyDeviceToDevice, stream);
    k_gemm_bt<false><<<dim3(L / 128, DV / 128, NBATCH), 256, 0, stream>>>(
        mvh, pp, (void*)memOut, DV, L, L, 1.f / PSCALE);
    for (int b = 0; b < NBATCH; ++b) {
      const f16* src = (b == 3) ? bounce : (pp + (size_t)b * LL);
      k_tr_out<<<dim3(L / 64, L / 64), 256, 0, stream>>>(
          src, pOut + (size_t)b * LL, 1.f / PSCALE);
    }
  }
  (void)in_sizes; (void)n_in; (void)out_size; (void)ws_size;
}

// Round 5
// 222.460 us; speedup vs baseline: 1.4473x; 1.2111x over previous
//
#include <hip/hip_runtime.h>
#include <hip/hip_fp16.h>
#include <math.h>

typedef _Float16 f16;
typedef __attribute__((ext_vector_type(4))) _Float16 f16x4;
typedef __attribute__((ext_vector_type(8))) _Float16 f16x8;
typedef __attribute__((ext_vector_type(4))) float f32x4;

static constexpr int NBATCH = 4, DK = 128, DV = 512, L = 4096;
static constexpr float PSCALE = 256.f; // fallback path only

__device__ __forceinline__ void async16(const void* g, void* l) {
  __builtin_amdgcn_global_load_lds((const __attribute__((address_space(1))) void*)g,
                                   (__attribute__((address_space(3))) void*)l, 16, 0, 0);
}

// combined input transposes: z<4 -> q_k batch z, z>=4 -> m_k batch z-4
// [DK][L] f32 -> [L][DK] f16
__global__ void k_tr2(const float* __restrict__ qk, const float* __restrict__ mk,
                      f16* __restrict__ qkT, f16* __restrict__ mkT) {
  __shared__ float tile[32][33];
  const int z = blockIdx.z;
  const size_t bs = (size_t)DK * L;
  const float* inb = (z < 4 ? qk : mk) + (size_t)(z & 3) * bs;
  f16* outb = (z < 4 ? qkT : mkT) + (size_t)(z & 3) * bs;
  const int c0 = blockIdx.x * 32, r0 = blockIdx.y * 32;
  const int tx = threadIdx.x, ty = threadIdx.y;
#pragma unroll
  for (int i = 0; i < 32; i += 8)
    tile[ty + i][tx] = inb[(size_t)(r0 + ty + i) * L + (c0 + tx)];
  __syncthreads();
#pragma unroll
  for (int i = 0; i < 32; i += 8)
    outb[(size_t)(c0 + ty + i) * DK + (r0 + tx)] = (f16)tile[tx][ty + i];
}

__global__ void k_cvt_f16(const float4* __restrict__ in, f16x4* __restrict__ out, int n4) {
  int i = blockIdx.x * blockDim.x + threadIdx.x;
  const int st = gridDim.x * blockDim.x;
  for (; i < n4; i += st) {
    float4 v = in[i];
    f16x4 o;
    o.x = (f16)v.x; o.y = (f16)v.y; o.z = (f16)v.z; o.w = (f16)v.w;
    out[i] = o;
  }
}

// C[z][row][col] = f(sum_k A[z][row][k] * B[z][col][k])
// A:[M][K] f16 row-major, B:[N][K] f16 row-major (both K-contiguous).
// 128x128 tile, BK=64, 4 waves (2x2), global_load_lds + XOR-source-swizzle.
// MODE 0 (QK): writes e' = exp(s*oscale) f16 + per-block row expsum partials.
// MODE 1 (PV): f32 out scaled by aux[col] (rowinv); by-fastest XCD chunking;
//              fused p-writeback: block `by` owns m-quarter [1024*by,+1024);
//              during those 16 K-steps it transposes its LDS B-tile (= e')
//              scaled by rowinv into P[z][m][q] (256B-contiguous per store).
template<int MODE>
__global__ __launch_bounds__(256, 2)
void k_gemm(const f16* __restrict__ A, const f16* __restrict__ B,
            void* __restrict__ C, float* __restrict__ aux,
            float* __restrict__ P, int M, int N, int K, float oscale) {
  constexpr int BK = 64;
  __shared__ __align__(16) f16 As[128 * BK];
  __shared__ __align__(16) f16 Bs[128 * BK];
  __shared__ float sums[128];
  const int z = blockIdx.z;
  int bx = blockIdx.x, by = blockIdx.y;
  {
    const int n = gridDim.x * gridDim.y;
    const int id = bx + gridDim.x * by;
    const int id2 = (id & 7) * (n >> 3) + (id >> 3); // XCD chunk (n%8==0)
    if (MODE == 0) { bx = id2 % gridDim.x; by = id2 / gridDim.x; }
    else           { by = id2 % gridDim.y; bx = id2 / gridDim.y; }
  }
  const f16* Ab = A + (size_t)z * M * K;
  const f16* Bbp = B + (size_t)z * N * K;
  const int row0 = by * 128, col0 = bx * 128;
  const int tid = threadIdx.x, lane = tid & 63, wv = tid >> 6;
  const int wr = wv >> 1, wc = wv & 1;
  f32x4 acc[4][4] = {};
  const int srow = wv * 32 + (lane >> 3);
  const int sc = (lane & 7) ^ (lane >> 3); // source chunk pre-swizzle
  const f16* aSrc = Ab + (size_t)(row0 + srow) * K + sc * 8;
  const f16* bSrc = Bbp + (size_t)(col0 + srow) * K + sc * 8;
  f16* aDst = &As[(wv * 32) * BK];
  f16* bDst = &Bs[(wv * 32) * BK];
  float rv0 = 0.f, rv1 = 0.f;
  if (MODE == 1) {
    rv0 = aux[(size_t)z * L + col0 + lane];
    rv1 = aux[(size_t)z * L + col0 + 64 + lane];
  }

  for (int k0 = 0; k0 < K; k0 += BK) {
    __syncthreads();
#pragma unroll
    for (int j = 0; j < 4; ++j) {
      async16(aSrc + (size_t)(j * 8) * K + k0, aDst + (j * 8) * BK);
      async16(bSrc + (size_t)(j * 8) * K + k0, bDst + (j * 8) * BK);
    }
    __syncthreads();
#pragma unroll
    for (int kk = 0; kk < BK / 32; ++kk) {
      const int cx = ((kk * 4 + (lane >> 4)) ^ (lane & 7)) * 8;
      f16x8 av[4], bv[4];
#pragma unroll
      for (int i = 0; i < 4; ++i) {
        av[i] = *(const f16x8*)&As[(wr * 64 + i * 16 + (lane & 15)) * BK + cx];
        bv[i] = *(const f16x8*)&Bs[(wc * 64 + i * 16 + (lane & 15)) * BK + cx];
      }
#pragma unroll
      for (int i = 0; i < 4; ++i)
#pragma unroll
        for (int j = 0; j < 4; ++j)
          acc[i][j] = __builtin_amdgcn_mfma_f32_16x16x32_f16(av[i], bv[j], acc[i][j], 0, 0, 0);
    }
    if (MODE == 1) {
      // fused p-writeback from the LDS B-tile (protected by next top barrier)
      if ((k0 >> 10) == by) {
#pragma unroll
        for (int h = 0; h < 2; ++h) {
          const int cc = wv * 2 + h; // this wave's 8-m chunk (0..7)
#pragma unroll
          for (int qh = 0; qh < 2; ++qh) {
            const int q = qh * 64 + lane;
            const f16x8 ev =
                *(const f16x8*)&Bs[q * BK + ((cc ^ (q & 7)) * 8)];
            const float rv = qh ? rv1 : rv0;
            float* pr = P + (size_t)z * L * L + (size_t)(k0 + cc * 8) * L + col0 + q;
#pragma unroll
            for (int j = 0; j < 8; ++j)
              pr[(size_t)j * L] = (float)ev[j] * rv;
          }
        }
      }
    }
  }
  // C/D layout: col = lane&15, row = (lane>>4)*4 + t
  const size_t cb = (size_t)z * M * N;
  const int er = (lane >> 4) * 4, ec = lane & 15;
  if (MODE == 0) {
    // e' = exp(acc*oscale) f16 out + per-row expsum partials (no-max softmax)
    float rp[16];
#pragma unroll
    for (int u = 0; u < 16; ++u) rp[u] = 0.f;
#pragma unroll
    for (int i = 0; i < 4; ++i) {
      const int r = row0 + wr * 64 + i * 16 + er;
#pragma unroll
      for (int j = 0; j < 4; ++j) {
        const int c = col0 + wc * 64 + j * 16 + ec;
#pragma unroll
        for (int t = 0; t < 4; ++t) {
          const float e = __expf(acc[i][j][t] * oscale);
          ((f16*)C)[cb + (size_t)(r + t) * N + c] = (f16)e;
          rp[i * 4 + t] += e;
        }
      }
    }
#pragma unroll
    for (int u = 0; u < 16; ++u) {
      rp[u] += __shfl_xor(rp[u], 1);
      rp[u] += __shfl_xor(rp[u], 2);
      rp[u] += __shfl_xor(rp[u], 4);
      rp[u] += __shfl_xor(rp[u], 8);
    }
    // combine the two col-waves (wc): exactly 2 addends -> deterministic
    if (wc == 1 && (lane & 15) == 0) {
#pragma unroll
      for (int i = 0; i < 4; ++i)
#pragma unroll
        for (int t = 0; t < 4; ++t)
          sums[wr * 64 + i * 16 + (lane >> 4) * 4 + t] = rp[i * 4 + t];
    }
    __syncthreads();
    if (wc == 0 && (lane & 15) == 0) {
#pragma unroll
      for (int i = 0; i < 4; ++i)
#pragma unroll
        for (int t = 0; t < 4; ++t) {
          const int r = wr * 64 + i * 16 + (lane >> 4) * 4 + t;
          aux[((size_t)z * gridDim.x + bx) * L + row0 + r] = rp[i * 4 + t] + sums[r];
        }
    }
  } else {
    // PV: scale output columns by rowinv
    float rv[4];
#pragma unroll
    for (int j = 0; j < 4; ++j)
      rv[j] = aux[(size_t)z * L + col0 + wc * 64 + j * 16 + ec];
#pragma unroll
    for (int i = 0; i < 4; ++i) {
      const int r = row0 + wr * 64 + i * 16 + er;
#pragma unroll
      for (int j = 0; j < 4; ++j) {
        const int c = col0 + wc * 64 + j * 16 + ec;
#pragma unroll
        for (int t = 0; t < 4; ++t)
          ((float*)C)[cb + (size_t)(r + t) * N + c] = acc[i][j][t] * rv[j];
      }
    }
  }
}

// rowinv[z][q] = 1 / sum_bx partial[z][bx][q]
__global__ __launch_bounds__(256)
void k_rowsum(const float* __restrict__ partial, float* __restrict__ rowinv) {
  const int qi = blockIdx.x * 256 + threadIdx.x; // 0..16383
  const int z = qi >> 12, q = qi & 4095;
  float s = 0.f;
#pragma unroll
  for (int bx = 0; bx < 32; ++bx) s += partial[((size_t)z * 32 + bx) * L + q];
  rowinv[qi] = 1.f / s;
}

// ---------------- fallback-path kernels (proven round-1) ----------------
template<bool OUT_F16>
__global__ __launch_bounds__(256, 2)
void k_gemm_bt(const f16* __restrict__ A, const f16* __restrict__ B,
               void* __restrict__ C, int M, int N, int K, float oscale) {
  constexpr int BK = 64;
  __shared__ __align__(16) f16 As[128 * BK];
  __shared__ __align__(16) f16 Bs[128 * BK];
  const int z = blockIdx.z;
  const f16* Ab = A + (size_t)z * M * K;
  const f16* Bbp = B + (size_t)z * N * K;
  const int row0 = blockIdx.y * 128, col0 = blockIdx.x * 128;
  const int tid = threadIdx.x, lane = tid & 63, wv = tid >> 6;
  const int wr = wv >> 1, wc = wv & 1;
  f32x4 acc[4][4] = {};
  const int srow = wv * 32 + (lane >> 3);
  const int sc = (lane & 7) ^ (lane >> 3);
  const f16* aSrc = Ab + (size_t)(row0 + srow) * K + sc * 8;
  const f16* bSrc = Bbp + (size_t)(col0 + srow) * K + sc * 8;
  f16* aDst = &As[(wv * 32) * BK];
  f16* bDst = &Bs[(wv * 32) * BK];
  for (int k0 = 0; k0 < K; k0 += BK) {
    __syncthreads();
#pragma unroll
    for (int j = 0; j < 4; ++j) {
      async16(aSrc + (size_t)(j * 8) * K + k0, aDst + (j * 8) * BK);
      async16(bSrc + (size_t)(j * 8) * K + k0, bDst + (j * 8) * BK);
    }
    __syncthreads();
#pragma unroll
    for (int kk = 0; kk < BK / 32; ++kk) {
      const int cx = ((kk * 4 + (lane >> 4)) ^ (lane & 7)) * 8;
      f16x8 av[4], bv[4];
#pragma unroll
      for (int i = 0; i < 4; ++i) {
        av[i] = *(const f16x8*)&As[(wr * 64 + i * 16 + (lane & 15)) * BK + cx];
        bv[i] = *(const f16x8*)&Bs[(wc * 64 + i * 16 + (lane & 15)) * BK + cx];
      }
#pragma unroll
      for (int i = 0; i < 4; ++i)
#pragma unroll
        for (int j = 0; j < 4; ++j)
          acc[i][j] = __builtin_amdgcn_mfma_f32_16x16x32_f16(av[i], bv[j], acc[i][j], 0, 0, 0);
    }
  }
  const size_t cb = (size_t)z * M * N;
  const int er = (lane >> 4) * 4, ec = lane & 15;
#pragma unroll
  for (int i = 0; i < 4; ++i) {
    const int r = row0 + wr * 64 + i * 16 + er;
#pragma unroll
    for (int j = 0; j < 4; ++j) {
      const int c = col0 + wc * 64 + j * 16 + ec;
#pragma unroll
      for (int t = 0; t < 4; ++t) {
        const float v = acc[i][j][t] * oscale;
        if (OUT_F16) ((f16*)C)[cb + (size_t)(r + t) * N + c] = (f16)v;
        else        ((float*)C)[cb + (size_t)(r + t) * N + c] = v;
      }
    }
  }
}

__global__ __launch_bounds__(256)
void k_softmax(f16* __restrict__ S) {
  const size_t rowbase = (size_t)blockIdx.x * L;
  const int tid = threadIdx.x, ln = tid & 63, wv = tid >> 6;
  f16* p = S + rowbase + tid * 16;
  f16x8 v0 = *(const f16x8*)p;
  f16x8 v1 = *(const f16x8*)(p + 8);
  float x[16];
#pragma unroll
  for (int j = 0; j < 8; ++j) { x[j] = (float)v0[j]; x[8 + j] = (float)v1[j]; }
  float m = -3.0e38f;
#pragma unroll
  for (int j = 0; j < 16; ++j) m = fmaxf(m, x[j]);
#pragma unroll
  for (int off = 1; off < 64; off <<= 1) m = fmaxf(m, __shfl_xor(m, off));
  __shared__ float redm[4], reds[4];
  if (ln == 0) redm[wv] = m;
  __syncthreads();
  m = fmaxf(fmaxf(redm[0], redm[1]), fmaxf(redm[2], redm[3]));
  float s = 0.f;
#pragma unroll
  for (int j = 0; j < 16; ++j) { x[j] = __expf(x[j] - m); s += x[j]; }
#pragma unroll
  for (int off = 1; off < 64; off <<= 1) s += __shfl_xor(s, off);
  if (ln == 0) reds[wv] = s;
  __syncthreads();
  s = (reds[0] + reds[1]) + (reds[2] + reds[3]);
  const float k = PSCALE / s;
#pragma unroll
  for (int j = 0; j < 8; ++j) { v0[j] = (f16)(x[j] * k); v1[j] = (f16)(x[8 + j] * k); }
  *(f16x8*)p = v0;
  *(f16x8*)(p + 8) = v1;
}

__global__ __launch_bounds__(256)
void k_tr_out(const f16* __restrict__ src, float* __restrict__ dst, float scale) {
  __shared__ float tile[64][65];
  const int m0 = blockIdx.x * 64, q0 = blockIdx.y * 64;
  const int tid = threadIdx.x;
  const int r = tid >> 2, c4 = (tid & 3) * 16;
  const f16* sp = src + (size_t)(q0 + r) * L + m0 + c4;
  f16x8 a = *(const f16x8*)sp;
  f16x8 b = *(const f16x8*)(sp + 8);
#pragma unroll
  for (int j = 0; j < 8; ++j) {
    tile[c4 + j][r] = (float)a[j] * scale;
    tile[c4 + 8 + j][r] = (float)b[j] * scale;
  }
  __syncthreads();
  float* dp = dst + (size_t)(m0 + r) * L + q0 + c4;
#pragma unroll
  for (int g = 0; g < 4; ++g) {
    float4 w;
    w.x = tile[r][c4 + 4 * g + 0];
    w.y = tile[r][c4 + 4 * g + 1];
    w.z = tile[r][c4 + 4 * g + 2];
    w.w = tile[r][c4 + 4 * g + 3];
    *(float4*)(dp + 4 * g) = w;
  }
}

extern "C" void kernel_launch(void* const* d_in, const int* in_sizes, int n_in,
                              void* d_out, int out_size, void* d_ws, size_t ws_size,
                              hipStream_t stream) {
  const float* m_k = (const float*)d_in[0];
  const float* m_v = (const float*)d_in[1];
  const float* q_k = (const float*)d_in[2];
  char* ws = (char*)d_ws;
  float* memOut = (float*)d_out;                  // [B][Dv][L]
  float* pOut = memOut + (size_t)NBATCH * DV * L; // [B][L][L] f32
  const size_t LL = (size_t)L * L;

  const bool fused = ws_size >= ((size_t)160 << 20);
  if (fused) {
    f16* pp = (f16*)ws;                                   // 128 MiB e'
    float* partial = (float*)(ws + ((size_t)128 << 20));  // 2 MiB
    float* rowinv = (float*)(ws + ((size_t)130 << 20));   // 64 KiB
    f16* qkT = (f16*)(ws + ((size_t)131 << 20));          // 4 MiB
    f16* mkT = (f16*)(ws + ((size_t)135 << 20));          // 4 MiB
    f16* mvh = (f16*)(ws + ((size_t)139 << 20));          // 16 MiB
    k_tr2<<<dim3(L / 32, DK / 32, 8), dim3(32, 8), 0, stream>>>(q_k, m_k, qkT, mkT);
    k_cvt_f16<<<2048, 256, 0, stream>>>((const float4*)m_v, (f16x4*)mvh,
                                        NBATCH * DV * L / 4);
    // e'[q][m] = exp(s) f16 + per-block row expsum partials
    k_gemm<0><<<dim3(L / 128, L / 128, NBATCH), 256, 0, stream>>>(
        qkT, mkT, (void*)pp, partial, nullptr, L, L, DK, 0.08838834764831845f);
    k_rowsum<<<NBATCH * L / 256, 256, 0, stream>>>(partial, rowinv);
    // mem[v][q] = rowinv[q]*sum_m mv[v][m]*e'[q][m]; fused p[m][q] writeback
    k_gemm<1><<<dim3(L / 128, DV / 128, NBATCH), 256, 0, stream>>>(
        mvh, pp, (void*)memOut, rowinv, pOut, DV, L, L, 1.f);
  } else {
    // proven round-1 path
    f16* bounce = (f16*)ws;
    f16* qkT = (f16*)(ws + ((size_t)32 << 20));
    f16* mkT = (f16*)(ws + ((size_t)36 << 20));
    f16* mvh = (f16*)(ws + ((size_t)40 << 20));
    f16* pp = (f16*)(pOut + NBATCH * LL / 2);
    k_tr2<<<dim3(L / 32, DK / 32, 8), dim3(32, 8), 0, stream>>>(q_k, m_k, qkT, mkT);
    k_cvt_f16<<<2048, 256, 0, stream>>>((const float4*)m_v, (f16x4*)mvh,
                                        NBATCH * DV * L / 4);
    k_gemm_bt<true><<<dim3(L / 128, L / 128, NBATCH), 256, 0, stream>>>(
        qkT, mkT, (void*)pp, L, L, DK, 0.08838834764831845f);
    k_softmax<<<NBATCH * L, 256, 0, stream>>>(pp);
    hipMemcpyAsync(bounce, pp + 3 * LL, LL * sizeof(f16),
                   hipMemcpyDeviceToDevice, stream);
    k_gemm_bt<false><<<dim3(L / 128, DV / 128, NBATCH), 256, 0, stream>>>(
        mvh, pp, (void*)memOut, DV, L, L, 1.f / PSCALE);
    for (int b = 0; b < NBATCH; ++b) {
      const f16* src = (b == 3) ? bounce : (pp + (size_t)b * LL);
      k_tr_out<<<dim3(L / 64, L / 64), 256, 0, stream>>>(
          src, pOut + (size_t)b * LL, 1.f / PSCALE);
    }
  }
  (void)in_sizes; (void)n_in; (void)out_size; (void)ws_size;
}